// Round 12
// baseline (663.740 us; speedup 1.0000x reference)
//
#include <hip/hip_runtime.h>

#define NN 100000
#define EE 1600000
#define HIDD 128
#define TGTT 64
#define GGG 512
#define NBK 98          // buckets of 1024 nodes
#define CAPB 17408      // bucket capacity: mean 16327 +8.5 sd
#define ABLK 800        // binA blocks, EPB edges each
#define EPB 2000        // edges per binA block
#define CVT2 512        // cvt grid-stride blocks
#define LSTR 136        // sX row stride (shorts)
#define GBLK 782        // gmlp/projpool main blocks (128 rows)
#define FOUTB 64        // out filler blocks in k_gmlp (8 graphs each @512 thr)
#define OUTB 128        // k_out blocks (4 graphs each @256 thr)

typedef unsigned short ushort_t;
typedef __attribute__((ext_vector_type(8))) short short8;
typedef __attribute__((ext_vector_type(4))) float f32x4;
typedef __attribute__((ext_vector_type(4))) unsigned short us4;

__device__ __forceinline__ float b2f(ushort_t u) {
    union { unsigned int i; float f; } v; v.i = ((unsigned int)u) << 16; return v.f;
}
__device__ __forceinline__ ushort_t f2b(float f) {
    union { float f; unsigned int i; } v; v.f = f;
    unsigned int r = (v.i + 0x7fffu + ((v.i >> 16) & 1u)) >> 16;
    return (ushort_t)r;
}

// ======================= prologue: binA | cvt(grid-stride) | weight-prep | goff ============
__global__ __launch_bounds__(256) void k_pro(const float* __restrict__ x, ushort_t* __restrict__ Xb,
                                             const float* __restrict__ cw1, const float* __restrict__ cw2,
                                             const float* __restrict__ pw1, ushort_t* __restrict__ Wt,
                                             const int* __restrict__ batch, int* __restrict__ goff,
                                             const int* __restrict__ ei, int* __restrict__ gcnt,
                                             unsigned int* __restrict__ bbuf) {
    __shared__ int cnt[NBK], base[NBK], cur[NBK];
    int b = blockIdx.x, t = threadIdx.x;

    if (b < ABLK) {   // ---- binA edge binning
        if (t < NBK) cnt[t] = 0;
        __syncthreads();
        int e0 = b * EPB;
        int e1 = min(e0 + EPB, EE);
        for (int e = e0 + t; e < e1; e += 256)
            atomicAdd(&cnt[ei[EE + e] >> 10], 1);
        __syncthreads();
        if (t < NBK) { base[t] = atomicAdd(&gcnt[t], cnt[t]); cur[t] = 0; }
        __syncthreads();
        for (int e = e0 + t; e < e1; e += 256) {
            int s = ei[e], d = ei[EE + e];
            int bk = d >> 10;
            int off = base[bk] + atomicAdd(&cur[bk], 1);
            if (off < CAPB)
                bbuf[(long)bk * CAPB + off] = (unsigned int)s | (((unsigned int)d & 1023u) << 17);
        }
        return;
    }
    b -= ABLK;
    if (b < CVT2) {   // ---- x -> bf16, grid-stride streaming
        long total = (long)NN * HIDD / 4;
        long step = (long)CVT2 * 256;
        for (long i = (long)b * 256 + t; i < total; i += step) {
            float4 v = ((const float4*)x)[i];
            us4 o; o.x = f2b(v.x); o.y = f2b(v.y); o.z = f2b(v.z); o.w = f2b(v.w);
            ((us4*)Xb)[i] = o;
        }
        return;
    }
    b -= CVT2;
    if (b < 9) {      // ---- weight transpose: coalesced read, strided write
        int l = b / 3, j = b % 3;
        const float* src = (j == 0 ? cw1 : j == 1 ? cw2 : pw1) + (size_t)l * HIDD * HIDD;
        ushort_t* dst = Wt + (size_t)b * HIDD * HIDD;
        for (int i = t; i < HIDD * HIDD; i += 256)
            dst[(i & 127) * HIDD + (i >> 7)] = f2b(src[i]);
        return;
    }
    b -= 9;
    {                 // ---- goff binary search (3 blocks)
        int g = b * 256 + t;
        if (g > GGG) return;
        int lo = 0, hi = NN;
        while (lo < hi) { int mid = (lo + hi) >> 1; if (batch[mid] < g) lo = mid + 1; else hi = mid; }
        goff[g] = lo;
    }
}

// ======================= CSR phase B, 1024 threads (1 node/thread) =======================
__global__ __launch_bounds__(1024) void k_csr(const int* __restrict__ gcnt,
                                              const unsigned int* __restrict__ bbuf,
                                              int* __restrict__ rowptr, int* __restrict__ csr) {
    __shared__ int ldeg[1024], tsum[1024], sb[NBK];
    int b = blockIdx.x, t = threadIdx.x;
    if (t < NBK) sb[t] = gcnt[t];
    ldeg[t] = 0;
    __syncthreads();
    if (t == 0) { int a = 0; for (int i = 0; i < NBK; i++) { int v = sb[i]; sb[i] = a; a += v; } }
    __syncthreads();
    int cnt = min(gcnt[b], CAPB);
    int base = sb[b];
    const unsigned int* bb = bbuf + (long)b * CAPB;
    for (int i = t; i < cnt; i += 1024) atomicAdd(&ldeg[bb[i] >> 17], 1);
    __syncthreads();
    int d0 = ldeg[t];
    tsum[t] = d0;
    __syncthreads();
    for (int off = 1; off < 1024; off <<= 1) {
        int u = (t >= off) ? tsum[t - off] : 0;
        __syncthreads();
        tsum[t] += u;
        __syncthreads();
    }
    int p0 = base + tsum[t] - d0;
    int gnode = b * 1024 + t;
    if (gnode < NN) rowptr[gnode] = p0;
    if (b == NBK - 1 && t == 0) rowptr[NN] = EE;
    ldeg[t] = p0;          // reuse as scatter cursor
    __syncthreads();
    for (int i = t; i < cnt; i += 1024) {
        unsigned int en = bb[i];
        int pos = atomicAdd(&ldeg[en >> 17], 1);
        csr[pos] = (int)(en & 0x1FFFFu);
    }
}

// ======================= fused gather + 2-layer MLP — M=128, 512 thr, 128-VGPR budget =====
// Grid 782 = 3.05 blocks/CU; at 8 waves/block that's 24.4 waves/CU resident (2x the
// 256-thr version). launch_bounds(512,4): 4 waves/EU -> 2048/4... i.e. 128-VGPR budget,
// so the 8-deep gather unroll (~64 arch VGPR) does NOT spill (R1's failure was the
// (512,8) 64-reg budget). LDS unchanged 34.8KB (4 blocks/CU cap >= grid's 3.05).
__global__ __launch_bounds__(512, 4) void k_gmlp(const ushort_t* __restrict__ hin,
                                              const int* __restrict__ rowptr,
                                              const int* __restrict__ csr,
                                              const float* __restrict__ eps, int l,
                                              const ushort_t* __restrict__ Wt1, const float* __restrict__ B1,
                                              const ushort_t* __restrict__ Wt2, const float* __restrict__ B2,
                                              ushort_t* __restrict__ Y,
                                              const float* __restrict__ pooledP, const int* __restrict__ goff,
                                              const float* __restrict__ WoP, const float* __restrict__ BoP,
                                              float* __restrict__ outP, int lprev) {
    __shared__ ushort_t sX[128 * LSTR];
    int tid = threadIdx.x;

    if (blockIdx.x >= GBLK) {     // ---- filler: out[g] for previous layer (8 graphs/block)
        if (lprev < 0) return;
        int ob = blockIdx.x - GBLK;
        int sub = tid >> 6, tt = tid & 63;
        int g = ob * 8 + sub;
        if (g >= GGG) return;
        float cntg = (float)(goff[g + 1] - goff[g]);
        float acc = cntg * BoP[tt];
        const float* p = pooledP + (long)g * HIDD;
        for (int k = 0; k < HIDD; k++) acc += p[k] * WoP[k * TGTT + tt];
        outP[(long)g * (3 * TGTT) + lprev * TGTT + tt] = acc;
        return;
    }

    long base = (long)blockIdx.x * 128;
    int lane = tid & 15, ng = tid >> 4;   // 32 node-groups of 16 lanes
    int off = lane << 3;
    float e1 = 1.0f + eps[l];

    // ---- gather phase: 4 passes x 32 nodes (same 8-deep per-wave ILP as the 93us kernel)
#pragma unroll 1
    for (int it = 0; it < 4; it++) {
        int row = it * 32 + ng;
        long node = base + row;
        short8 o = (short8)0;
        if (node < NN) {
            short8 h = *(const short8*)(hin + (node << 7) + off);
            float acc[8];
#pragma unroll
            for (int t = 0; t < 8; t++) acc[t] = e1 * b2f((ushort_t)h[t]);
            int jb = rowptr[node], je = rowptr[node + 1];
            int j = jb;
            for (; j + 8 <= je; j += 8) {
                int s0 = csr[j], s1 = csr[j + 1], s2 = csr[j + 2], s3 = csr[j + 3];
                int s4 = csr[j + 4], s5 = csr[j + 5], s6 = csr[j + 6], s7 = csr[j + 7];
                short8 v0 = *(const short8*)(hin + ((long)s0 << 7) + off);
                short8 v1 = *(const short8*)(hin + ((long)s1 << 7) + off);
                short8 v2 = *(const short8*)(hin + ((long)s2 << 7) + off);
                short8 v3 = *(const short8*)(hin + ((long)s3 << 7) + off);
                short8 v4 = *(const short8*)(hin + ((long)s4 << 7) + off);
                short8 v5 = *(const short8*)(hin + ((long)s5 << 7) + off);
                short8 v6 = *(const short8*)(hin + ((long)s6 << 7) + off);
                short8 v7 = *(const short8*)(hin + ((long)s7 << 7) + off);
#pragma unroll
                for (int t = 0; t < 8; t++)
                    acc[t] += ((b2f((ushort_t)v0[t]) + b2f((ushort_t)v1[t])) +
                               (b2f((ushort_t)v2[t]) + b2f((ushort_t)v3[t]))) +
                              ((b2f((ushort_t)v4[t]) + b2f((ushort_t)v5[t])) +
                               (b2f((ushort_t)v6[t]) + b2f((ushort_t)v7[t])));
            }
            for (; j + 4 <= je; j += 4) {
                int s0 = csr[j], s1 = csr[j + 1], s2 = csr[j + 2], s3 = csr[j + 3];
                short8 v0 = *(const short8*)(hin + ((long)s0 << 7) + off);
                short8 v1 = *(const short8*)(hin + ((long)s1 << 7) + off);
                short8 v2 = *(const short8*)(hin + ((long)s2 << 7) + off);
                short8 v3 = *(const short8*)(hin + ((long)s3 << 7) + off);
#pragma unroll
                for (int t = 0; t < 8; t++)
                    acc[t] += (b2f((ushort_t)v0[t]) + b2f((ushort_t)v1[t])) +
                              (b2f((ushort_t)v2[t]) + b2f((ushort_t)v3[t]));
            }
            for (; j < je; j++) {
                int s = csr[j];
                short8 v = *(const short8*)(hin + ((long)s << 7) + off);
#pragma unroll
                for (int t = 0; t < 8; t++) acc[t] += b2f((ushort_t)v[t]);
            }
#pragma unroll
            for (int t = 0; t < 8; t++) o[t] = (short)f2b(acc[t]);
        }
        *(short8*)(sX + row * LSTR + off) = o;
    }
    __syncthreads();   // the only barrier: gather rows cross waves

    // ---- MLP: 8 waves x 1 private 16-row strip; no further barriers
    int w = tid >> 6, l64 = tid & 63, q = l64 >> 4, l16 = l64 & 15;
    int r0 = w * 16;
    short8 a0[4];
#pragma unroll
    for (int c = 0; c < 4; c++)
        a0[c] = *(const short8*)(sX + (r0 + l16) * LSTR + q * 8 + c * 32);
    f32x4 acc0[8];
#pragma unroll
    for (int nt = 0; nt < 8; nt++) {
        int col = nt * 16 + l16;
        float bias = B1[col];
        f32x4 c0 = {bias, bias, bias, bias};
        const ushort_t* bB = Wt1 + col * HIDD + q * 8;
#pragma unroll
        for (int c = 0; c < 4; c++) {
            short8 b = *(const short8*)(bB + c * 32);
            c0 = __builtin_amdgcn_mfma_f32_16x16x32_bf16(a0[c], b, c0, 0, 0, 0);
        }
        acc0[nt] = c0;
    }
    // T = relu(acc) -> own strip (wave-private)
#pragma unroll
    for (int nt = 0; nt < 8; nt++) {
        int col = nt * 16 + l16;
#pragma unroll
        for (int r = 0; r < 4; r++)
            sX[(r0 + q * 4 + r) * LSTR + col] = f2b(fmaxf(acc0[nt][r], 0.f));
    }
    // GEMM2: T @ Wt2 + B2 -> Y (reads own strip)
#pragma unroll
    for (int c = 0; c < 4; c++)
        a0[c] = *(const short8*)(sX + (r0 + l16) * LSTR + q * 8 + c * 32);
#pragma unroll
    for (int nt = 0; nt < 8; nt++) {
        int col = nt * 16 + l16;
        float bias = B2[col];
        f32x4 c0 = {bias, bias, bias, bias};
        const ushort_t* bB = Wt2 + col * HIDD + q * 8;
#pragma unroll
        for (int c = 0; c < 4; c++) {
            short8 b = *(const short8*)(bB + c * 32);
            c0 = __builtin_amdgcn_mfma_f32_16x16x32_bf16(a0[c], b, c0, 0, 0, 0);
        }
#pragma unroll
        for (int r = 0; r < 4; r++) {
            long row0 = base + r0 + q * 4 + r;
            if (row0 < NN) Y[(row0 << 7) + col] = f2b(c0[r]);
        }
    }
}

// ======================= GraphNorm stats -> affine coefficients A,B (R11 verbatim) ========
__global__ __launch_bounds__(512) void k_gstat(const ushort_t* __restrict__ Hraw,
                                               const int* __restrict__ goff,
                                               const float* __restrict__ scale,
                                               const float* __restrict__ weight,
                                               const float* __restrict__ gnb,
                                               float* __restrict__ Ab, float* __restrict__ Bb,
                                               float* __restrict__ pooled) {
    __shared__ float red[2][32][128];
    int g = blockIdx.x;
    int s = goff[g], e = goff[g + 1];
    float cnt = (float)max(e - s, 1);
    int lane = threadIdx.x & 15;   // 8-feature group
    int rg = threadIdx.x >> 4;     // 0..31 row groups
    int f0 = lane << 3;
    float sum[8], sq[8];
#pragma unroll
    for (int t = 0; t < 8; t++) { sum[t] = 0.f; sq[t] = 0.f; }
    for (int i = s + rg; i < e; i += 32) {
        short8 v = *(const short8*)(Hraw + ((long)i << 7) + f0);
#pragma unroll
        for (int t = 0; t < 8; t++) { float a = b2f((ushort_t)v[t]); sum[t] += a; sq[t] += a * a; }
    }
#pragma unroll
    for (int t = 0; t < 8; t++) { red[0][rg][f0 + t] = sum[t]; red[1][rg][f0 + t] = sq[t]; }
    __syncthreads();
    for (int off = 16; off > 0; off >>= 1) {
        if (rg < off) {
#pragma unroll
            for (int t = 0; t < 8; t++) {
                red[0][rg][f0 + t] += red[0][rg + off][f0 + t];
                red[1][rg][f0 + t] += red[1][rg + off][f0 + t];
            }
        }
        __syncthreads();
    }
    if (rg == 0) {
#pragma unroll
        for (int t = 0; t < 8; t++) {
            int f = f0 + t;
            float mean = red[0][0][f] / cnt;
            float ms = mean * scale[f];
            float var = red[1][0][f] / cnt - 2.f * ms * mean + ms * ms;
            float A = weight[f] / sqrtf(var + 1e-8f);
            Ab[g * HIDD + f] = A;
            Bb[g * HIDD + f] = gnb[f] - ms * A;
            pooled[g * HIDD + f] = 0.f;
        }
    }
}

// ======================= norm-apply + projection GEMM + pooling (R11 verbatim) ============
__global__ __launch_bounds__(256) void k_projpool(const ushort_t* __restrict__ Hraw,
                                                  const int* __restrict__ batch,
                                                  const float* __restrict__ Ab, const float* __restrict__ Bb,
                                                  const ushort_t* __restrict__ Wt, const float* __restrict__ B,
                                                  ushort_t* __restrict__ Hn, float* __restrict__ pooled,
                                                  int store_hn) {
    __shared__ ushort_t sX[128 * LSTR];
    __shared__ int sgid[128];
    __shared__ float sA[4][128], sB[4][128];
    int tid = threadIdx.x;
    long base = (long)blockIdx.x * 128;

    if (tid < 128) sgid[tid] = (base + tid < NN) ? batch[base + tid] : -1;
    __syncthreads();
    int gmin = sgid[0];
    {
        int f = tid & 127;
#pragma unroll
        for (int s = tid >> 7; s < 4; s += 2) {
            int gg = gmin + s;
            if (gg < GGG) {
                sA[s][f] = Ab[(long)gg * HIDD + f];
                sB[s][f] = Bb[(long)gg * HIDD + f];
            }
        }
    }
    __syncthreads();

#pragma unroll
    for (int c = 0; c < 8; c++) {
        int idx = c * 256 + tid;
        int row = idx >> 4, cw = idx & 15;
        long grow = base + row;
        short8 v = (short8)0;
        if (grow < NN) {
            short8 raw = *(const short8*)(Hraw + (grow << 7) + (cw << 3));
            int slot = sgid[row] - gmin;
            const float* pA = &sA[slot][cw << 3];
            const float* pB = &sB[slot][cw << 3];
#pragma unroll
            for (int t = 0; t < 8; t++) {
                float val = b2f((ushort_t)raw[t]) * pA[t] + pB[t];
                v[t] = (short)f2b(val > 0.f ? val : 0.f);
            }
            if (store_hn) *(short8*)(Hn + (grow << 7) + (cw << 3)) = v;
        }
        *(short8*)(sX + row * LSTR + (cw << 3)) = v;
    }
    __syncthreads();   // staging wrote rows across waves

    int w = tid >> 6, l64 = tid & 63, q = l64 >> 4, l16 = l64 & 15;
    int r0 = w * 16, r1 = 64 + w * 16;
    short8 a0[4], a1[4];
#pragma unroll
    for (int c = 0; c < 4; c++) {
        a0[c] = *(const short8*)(sX + (r0 + l16) * LSTR + q * 8 + c * 32);
        a1[c] = *(const short8*)(sX + (r1 + l16) * LSTR + q * 8 + c * 32);
    }
    f32x4 acc0[8], acc1[8];
#pragma unroll
    for (int nt = 0; nt < 8; nt++) {
        int col = nt * 16 + l16;
        float bias = B[col];
        f32x4 c0 = {bias, bias, bias, bias};
        f32x4 c1 = c0;
        const ushort_t* bB = Wt + col * HIDD + q * 8;
#pragma unroll
        for (int c = 0; c < 4; c++) {
            short8 b = *(const short8*)(bB + c * 32);
            c0 = __builtin_amdgcn_mfma_f32_16x16x32_bf16(a0[c], b, c0, 0, 0, 0);
            c1 = __builtin_amdgcn_mfma_f32_16x16x32_bf16(a1[c], b, c1, 0, 0, 0);
        }
        acc0[nt] = c0; acc1[nt] = c1;
    }
    // z = relu(acc) -> own strips (wave-private; no barrier before this)
#pragma unroll
    for (int nt = 0; nt < 8; nt++) {
        int col = nt * 16 + l16;
#pragma unroll
        for (int r = 0; r < 4; r++) {
            sX[(r0 + q * 4 + r) * LSTR + col] = f2b(fmaxf(acc0[nt][r], 0.f));
            sX[(r1 + q * 4 + r) * LSTR + col] = f2b(fmaxf(acc1[nt][r], 0.f));
        }
    }
    __syncthreads();   // pooling reads all rows

    int f = tid & 127, half = tid >> 7;
    int rbeg = half * 64, rend = rbeg + 64;
    float sum = 0.f;
    int curg = -1;
    for (int row = rbeg; row < rend; row++) {
        int g = sgid[row];
        if (g != curg) {
            if (curg >= 0) atomicAdd(&pooled[(long)curg * HIDD + f], sum);
            sum = 0.f; curg = g;
        }
        if (g >= 0) sum += b2f(sX[row * LSTR + f]);
    }
    if (curg >= 0) atomicAdd(&pooled[(long)curg * HIDD + f], sum);
}

// ---- final out (layer 2): 4 graphs per 256-thread block
__global__ __launch_bounds__(256) void k_out(const float* __restrict__ pooled, const int* __restrict__ goff,
                                             const float* __restrict__ W, const float* __restrict__ B,
                                             float* __restrict__ out, int l) {
    int sub = threadIdx.x >> 6, tt = threadIdx.x & 63;
    int g = blockIdx.x * 4 + sub;
    if (g >= GGG) return;
    float cnt = (float)(goff[g + 1] - goff[g]);
    float acc = cnt * B[tt];
    const float* p = pooled + (long)g * HIDD;
    for (int k = 0; k < HIDD; k++) acc += p[k] * W[k * TGTT + tt];
    out[(long)g * (3 * TGTT) + l * TGTT + tt] = acc;
}

extern "C" void kernel_launch(void* const* d_in, const int* in_sizes, int n_in,
                              void* d_out, int out_size, void* d_ws, size_t ws_size,
                              hipStream_t stream) {
    const float* x    = (const float*)d_in[0];
    const int*   ei   = (const int*)d_in[1];
    const int*   batch= (const int*)d_in[2];
    const float* cw1  = (const float*)d_in[3];
    const float* cb1  = (const float*)d_in[4];
    const float* cw2  = (const float*)d_in[5];
    const float* cb2  = (const float*)d_in[6];
    const float* eps  = (const float*)d_in[7];
    const float* gsc  = (const float*)d_in[8];
    const float* gw   = (const float*)d_in[9];
    const float* gb   = (const float*)d_in[10];
    const float* pw1  = (const float*)d_in[11];
    const float* pb1  = (const float*)d_in[12];
    const float* pw2  = (const float*)d_in[13];
    const float* pb2  = (const float*)d_in[14];
    float* out = (float*)d_out;

    // Workspace layout IDENTICAL to R0/R9/R10/R11.
    ushort_t* Xb   = (ushort_t*)d_ws;                       // N*128 bf16 — aliases Hn
    ushort_t* Hn   = Xb;
    ushort_t* Hraw = Xb + (size_t)NN * HIDD;                // N*128 bf16
    ushort_t* Wt   = Hraw + (size_t)NN * HIDD;              // 9*128*128 bf16
    float* Ab      = (float*)(Wt + (size_t)9 * HIDD * HIDD);// G*128 f32
    float* Bb      = Ab + (size_t)GGG * HIDD;               // G*128 f32
    float* pooled  = Bb + (size_t)GGG * HIDD;               // G*128 f32
    int* goff   = (int*)(pooled + (size_t)GGG * HIDD);      // G+1
    int* rowptr = goff + (GGG + 1);                         // N+1
    int* gcnt   = rowptr + (NN + 1);                        // NBK
    int* csr    = gcnt + NBK;                               // E
    unsigned int* bbuf = (unsigned int*)(csr + EE);         // NBK*CAPB

    hipMemsetAsync(gcnt, 0, NBK * sizeof(int), stream);
    k_pro<<<ABLK + CVT2 + 9 + 3, 256, 0, stream>>>(x, Xb, cw1, cw2, pw1, Wt, batch, goff, ei, gcnt, bbuf);
    k_csr<<<NBK, 1024, 0, stream>>>(gcnt, bbuf, rowptr, csr);

    for (int l = 0; l < 3; l++) {
        const ushort_t* hin = (l == 0) ? Xb : Hn;
        ushort_t* Wt1 = Wt + (size_t)(l * 3 + 0) * HIDD * HIDD;
        ushort_t* Wt2 = Wt + (size_t)(l * 3 + 1) * HIDD * HIDD;
        ushort_t* Wtp = Wt + (size_t)(l * 3 + 2) * HIDD * HIDD;
        int grid = GBLK + (l > 0 ? FOUTB : 0);
        k_gmlp<<<grid, 512, 0, stream>>>(hin, rowptr, csr, eps, l,
                                         Wt1, cb1 + l * HIDD, Wt2, cb2 + l * HIDD, Hraw,
                                         pooled, goff,
                                         pw2 + (size_t)(l - 1) * HIDD * TGTT, pb2 + (l - 1) * TGTT,
                                         out, l - 1);
        k_gstat<<<GGG, 512, 0, stream>>>(Hraw, goff, gsc + l * HIDD, gw + l * HIDD, gb + l * HIDD,
                                         Ab, Bb, pooled);
        k_projpool<<<GBLK, 256, 0, stream>>>(Hraw, batch, Ab, Bb,
                                             Wtp, pb1 + l * HIDD, Hn, pooled, (l < 2) ? 1 : 0);
    }
    k_out<<<OUTB, 256, 0, stream>>>(pooled, goff, pw2 + (size_t)2 * HIDD * TGTT, pb2 + 2 * TGTT, out, 2);
}

// Round 13
// 589.720 us; speedup vs baseline: 1.1255x; 1.1255x over previous
//
#include <hip/hip_runtime.h>

#define NN 100000
#define EE 1600000
#define HIDD 128
#define TGTT 64
#define GGG 512
#define NBK 98          // buckets of 1024 nodes
#define CAPB 17408      // bucket capacity: mean 16327 +8.5 sd
#define ABLK 800        // binA blocks, EPB edges each
#define EPB 2000        // edges per binA block
#define CVT2 512        // cvt grid-stride blocks
#define LSTR 136        // sX row stride (shorts)
#define GBLK 782        // gmlp/projpool main blocks (128 rows)
#define OUTB 128        // out filler blocks (4 graphs each @256 thr)

typedef unsigned short ushort_t;
typedef __attribute__((ext_vector_type(8))) short short8;
typedef __attribute__((ext_vector_type(4))) float f32x4;
typedef __attribute__((ext_vector_type(4))) unsigned short us4;

__device__ __forceinline__ float b2f(ushort_t u) {
    union { unsigned int i; float f; } v; v.i = ((unsigned int)u) << 16; return v.f;
}
__device__ __forceinline__ ushort_t f2b(float f) {
    union { float f; unsigned int i; } v; v.f = f;
    unsigned int r = (v.i + 0x7fffu + ((v.i >> 16) & 1u)) >> 16;
    return (ushort_t)r;
}

// ======================= prologue: binA | cvt(grid-stride) | weight-prep | goff ============
__global__ __launch_bounds__(256) void k_pro(const float* __restrict__ x, ushort_t* __restrict__ Xb,
                                             const float* __restrict__ cw1, const float* __restrict__ cw2,
                                             const float* __restrict__ pw1, ushort_t* __restrict__ Wt,
                                             const int* __restrict__ batch, int* __restrict__ goff,
                                             const int* __restrict__ ei, int* __restrict__ gcnt,
                                             unsigned int* __restrict__ bbuf) {
    __shared__ int cnt[NBK], base[NBK], cur[NBK];
    int b = blockIdx.x, t = threadIdx.x;

    if (b < ABLK) {   // ---- binA edge binning
        if (t < NBK) cnt[t] = 0;
        __syncthreads();
        int e0 = b * EPB;
        int e1 = min(e0 + EPB, EE);
        for (int e = e0 + t; e < e1; e += 256)
            atomicAdd(&cnt[ei[EE + e] >> 10], 1);
        __syncthreads();
        if (t < NBK) { base[t] = atomicAdd(&gcnt[t], cnt[t]); cur[t] = 0; }
        __syncthreads();
        for (int e = e0 + t; e < e1; e += 256) {
            int s = ei[e], d = ei[EE + e];
            int bk = d >> 10;
            int off = base[bk] + atomicAdd(&cur[bk], 1);
            if (off < CAPB)
                bbuf[(long)bk * CAPB + off] = (unsigned int)s | (((unsigned int)d & 1023u) << 17);
        }
        return;
    }
    b -= ABLK;
    if (b < CVT2) {   // ---- x -> bf16, grid-stride streaming
        long total = (long)NN * HIDD / 4;
        long step = (long)CVT2 * 256;
        for (long i = (long)b * 256 + t; i < total; i += step) {
            float4 v = ((const float4*)x)[i];
            us4 o; o.x = f2b(v.x); o.y = f2b(v.y); o.z = f2b(v.z); o.w = f2b(v.w);
            ((us4*)Xb)[i] = o;
        }
        return;
    }
    b -= CVT2;
    if (b < 9) {      // ---- weight transpose: coalesced read, strided write
        int l = b / 3, j = b % 3;
        const float* src = (j == 0 ? cw1 : j == 1 ? cw2 : pw1) + (size_t)l * HIDD * HIDD;
        ushort_t* dst = Wt + (size_t)b * HIDD * HIDD;
        for (int i = t; i < HIDD * HIDD; i += 256)
            dst[(i & 127) * HIDD + (i >> 7)] = f2b(src[i]);
        return;
    }
    b -= 9;
    {                 // ---- goff binary search (3 blocks)
        int g = b * 256 + t;
        if (g > GGG) return;
        int lo = 0, hi = NN;
        while (lo < hi) { int mid = (lo + hi) >> 1; if (batch[mid] < g) lo = mid + 1; else hi = mid; }
        goff[g] = lo;
    }
}

// ======================= CSR phase B, 1024 threads (1 node/thread) =======================
__global__ __launch_bounds__(1024) void k_csr(const int* __restrict__ gcnt,
                                              const unsigned int* __restrict__ bbuf,
                                              int* __restrict__ rowptr, int* __restrict__ csr) {
    __shared__ int ldeg[1024], tsum[1024], sb[NBK];
    int b = blockIdx.x, t = threadIdx.x;
    if (t < NBK) sb[t] = gcnt[t];
    ldeg[t] = 0;
    __syncthreads();
    if (t == 0) { int a = 0; for (int i = 0; i < NBK; i++) { int v = sb[i]; sb[i] = a; a += v; } }
    __syncthreads();
    int cnt = min(gcnt[b], CAPB);
    int base = sb[b];
    const unsigned int* bb = bbuf + (long)b * CAPB;
    for (int i = t; i < cnt; i += 1024) atomicAdd(&ldeg[bb[i] >> 17], 1);
    __syncthreads();
    int d0 = ldeg[t];
    tsum[t] = d0;
    __syncthreads();
    for (int off = 1; off < 1024; off <<= 1) {
        int u = (t >= off) ? tsum[t - off] : 0;
        __syncthreads();
        tsum[t] += u;
        __syncthreads();
    }
    int p0 = base + tsum[t] - d0;
    int gnode = b * 1024 + t;
    if (gnode < NN) rowptr[gnode] = p0;
    if (b == NBK - 1 && t == 0) rowptr[NN] = EE;
    ldeg[t] = p0;          // reuse as scatter cursor
    __syncthreads();
    for (int i = t; i < cnt; i += 1024) {
        unsigned int en = bb[i];
        int pos = atomicAdd(&ldeg[en >> 17], 1);
        csr[pos] = (int)(en & 0x1FFFFu);
    }
}

// ======================= fused gather + 2-layer MLP + GraphNorm stats =====================
// R9/R11 gather+MLP verbatim (93.0us measured, 256thr/M=128) + R5-validated stats epilogue:
// GEMM2 writes h to Y AND to sX (wave-private rows), then one barrier + segmented per-graph
// (sum,sumsq) reduce -> f32 atomics into gsum/gsq. Replaces the whole 12us/layer k_gstat.
__global__ __launch_bounds__(256) void k_gmlp(const ushort_t* __restrict__ hin,
                                              const int* __restrict__ rowptr,
                                              const int* __restrict__ csr,
                                              const int* __restrict__ batch,
                                              const float* __restrict__ eps, int l,
                                              const ushort_t* __restrict__ Wt1, const float* __restrict__ B1,
                                              const ushort_t* __restrict__ Wt2, const float* __restrict__ B2,
                                              ushort_t* __restrict__ Y,
                                              float* __restrict__ gsum, float* __restrict__ gsq,
                                              const float* __restrict__ pooledP, const int* __restrict__ goff,
                                              const float* __restrict__ WoP, const float* __restrict__ BoP,
                                              float* __restrict__ outP, int lprev) {
    __shared__ ushort_t sX[128 * LSTR];
    __shared__ int sgid[128];
    int tid = threadIdx.x;

    if (blockIdx.x >= GBLK) {     // ---- filler: out[g] for previous layer (4 graphs/block)
        if (lprev < 0) return;
        int ob = blockIdx.x - GBLK;
        int sub = tid >> 6, tt = tid & 63;
        int g = ob * 4 + sub;
        if (g >= GGG) return;
        float cntg = (float)(goff[g + 1] - goff[g]);
        float acc = cntg * BoP[tt];
        const float* p = pooledP + (long)g * HIDD;
        for (int k = 0; k < HIDD; k++) acc += p[k] * WoP[k * TGTT + tt];
        outP[(long)g * (3 * TGTT) + lprev * TGTT + tt] = acc;
        return;
    }

    long base = (long)blockIdx.x * 128;
    int lane = tid & 15, ng = tid >> 4;
    int off = lane << 3;
    float e1 = 1.0f + eps[l];

    if (tid < 128) sgid[tid] = (base + tid < NN) ? batch[base + tid] : -1;

    // ---- gather phase: 8 passes x 16 nodes (R9 verbatim)
#pragma unroll 1
    for (int it = 0; it < 8; it++) {
        int row = it * 16 + ng;
        long node = base + row;
        short8 o = (short8)0;
        if (node < NN) {
            short8 h = *(const short8*)(hin + (node << 7) + off);
            float acc[8];
#pragma unroll
            for (int t = 0; t < 8; t++) acc[t] = e1 * b2f((ushort_t)h[t]);
            int jb = rowptr[node], je = rowptr[node + 1];
            int j = jb;
            for (; j + 8 <= je; j += 8) {
                int s0 = csr[j], s1 = csr[j + 1], s2 = csr[j + 2], s3 = csr[j + 3];
                int s4 = csr[j + 4], s5 = csr[j + 5], s6 = csr[j + 6], s7 = csr[j + 7];
                short8 v0 = *(const short8*)(hin + ((long)s0 << 7) + off);
                short8 v1 = *(const short8*)(hin + ((long)s1 << 7) + off);
                short8 v2 = *(const short8*)(hin + ((long)s2 << 7) + off);
                short8 v3 = *(const short8*)(hin + ((long)s3 << 7) + off);
                short8 v4 = *(const short8*)(hin + ((long)s4 << 7) + off);
                short8 v5 = *(const short8*)(hin + ((long)s5 << 7) + off);
                short8 v6 = *(const short8*)(hin + ((long)s6 << 7) + off);
                short8 v7 = *(const short8*)(hin + ((long)s7 << 7) + off);
#pragma unroll
                for (int t = 0; t < 8; t++)
                    acc[t] += ((b2f((ushort_t)v0[t]) + b2f((ushort_t)v1[t])) +
                               (b2f((ushort_t)v2[t]) + b2f((ushort_t)v3[t]))) +
                              ((b2f((ushort_t)v4[t]) + b2f((ushort_t)v5[t])) +
                               (b2f((ushort_t)v6[t]) + b2f((ushort_t)v7[t])));
            }
            for (; j + 4 <= je; j += 4) {
                int s0 = csr[j], s1 = csr[j + 1], s2 = csr[j + 2], s3 = csr[j + 3];
                short8 v0 = *(const short8*)(hin + ((long)s0 << 7) + off);
                short8 v1 = *(const short8*)(hin + ((long)s1 << 7) + off);
                short8 v2 = *(const short8*)(hin + ((long)s2 << 7) + off);
                short8 v3 = *(const short8*)(hin + ((long)s3 << 7) + off);
#pragma unroll
                for (int t = 0; t < 8; t++)
                    acc[t] += (b2f((ushort_t)v0[t]) + b2f((ushort_t)v1[t])) +
                              (b2f((ushort_t)v2[t]) + b2f((ushort_t)v3[t]));
            }
            for (; j < je; j++) {
                int s = csr[j];
                short8 v = *(const short8*)(hin + ((long)s << 7) + off);
#pragma unroll
                for (int t = 0; t < 8; t++) acc[t] += b2f((ushort_t)v[t]);
            }
#pragma unroll
            for (int t = 0; t < 8; t++) o[t] = (short)f2b(acc[t]);
        }
        *(short8*)(sX + row * LSTR + off) = o;
    }
    __syncthreads();   // gather rows cross waves

    // ---- MLP: 4 waves x 2 private strips; no barriers until stats
    int w = tid >> 6, l64 = tid & 63, q = l64 >> 4, l16 = l64 & 15;
    int r0 = w * 16, r1 = 64 + w * 16;
    short8 a0[4], a1[4];
#pragma unroll
    for (int c = 0; c < 4; c++) {
        a0[c] = *(const short8*)(sX + (r0 + l16) * LSTR + q * 8 + c * 32);
        a1[c] = *(const short8*)(sX + (r1 + l16) * LSTR + q * 8 + c * 32);
    }
    f32x4 acc0[8], acc1[8];
#pragma unroll
    for (int nt = 0; nt < 8; nt++) {
        int col = nt * 16 + l16;
        float bias = B1[col];
        f32x4 c0 = {bias, bias, bias, bias};
        f32x4 c1 = c0;
        const ushort_t* bB = Wt1 + col * HIDD + q * 8;
#pragma unroll
        for (int c = 0; c < 4; c++) {
            short8 b = *(const short8*)(bB + c * 32);
            c0 = __builtin_amdgcn_mfma_f32_16x16x32_bf16(a0[c], b, c0, 0, 0, 0);
            c1 = __builtin_amdgcn_mfma_f32_16x16x32_bf16(a1[c], b, c1, 0, 0, 0);
        }
        acc0[nt] = c0; acc1[nt] = c1;
    }
    // T = relu(acc) -> own strips (wave-private)
#pragma unroll
    for (int nt = 0; nt < 8; nt++) {
        int col = nt * 16 + l16;
#pragma unroll
        for (int r = 0; r < 4; r++) {
            sX[(r0 + q * 4 + r) * LSTR + col] = f2b(fmaxf(acc0[nt][r], 0.f));
            sX[(r1 + q * 4 + r) * LSTR + col] = f2b(fmaxf(acc1[nt][r], 0.f));
        }
    }
    // GEMM2: T @ Wt2 + B2 -> Y (global) and h -> sX (wave-private rows, for stats)
#pragma unroll
    for (int c = 0; c < 4; c++) {
        a0[c] = *(const short8*)(sX + (r0 + l16) * LSTR + q * 8 + c * 32);
        a1[c] = *(const short8*)(sX + (r1 + l16) * LSTR + q * 8 + c * 32);
    }
#pragma unroll
    for (int nt = 0; nt < 8; nt++) {
        int col = nt * 16 + l16;
        float bias = B2[col];
        f32x4 c0 = {bias, bias, bias, bias};
        f32x4 c1 = c0;
        const ushort_t* bB = Wt2 + col * HIDD + q * 8;
#pragma unroll
        for (int c = 0; c < 4; c++) {
            short8 b = *(const short8*)(bB + c * 32);
            c0 = __builtin_amdgcn_mfma_f32_16x16x32_bf16(a0[c], b, c0, 0, 0, 0);
            c1 = __builtin_amdgcn_mfma_f32_16x16x32_bf16(a1[c], b, c1, 0, 0, 0);
        }
#pragma unroll
        for (int r = 0; r < 4; r++) {
            long row0 = base + r0 + q * 4 + r;
            long row1 = base + r1 + q * 4 + r;
            ushort_t h0 = f2b(c0[r]), h1 = f2b(c1[r]);
            if (row0 < NN) Y[(row0 << 7) + col] = h0;
            if (row1 < NN) Y[(row1 << 7) + col] = h1;
            sX[(r0 + q * 4 + r) * LSTR + col] = h0;
            sX[(r1 + q * 4 + r) * LSTR + col] = h1;
        }
    }
    __syncthreads();   // stats read all rows (+ sgid visible)

    // ---- segmented per-graph (sum, sumsq) -> atomics (R5-validated pattern)
    int f = tid & 127, half = tid >> 7;
    int rbeg = half * 64, rend = rbeg + 64;
    float s1 = 0.f, s2 = 0.f;
    int curg = -1;
    for (int row = rbeg; row < rend; row++) {
        int g = sgid[row];
        if (g != curg) {
            if (curg >= 0) {
                atomicAdd(&gsum[(long)curg * HIDD + f], s1);
                atomicAdd(&gsq[(long)curg * HIDD + f], s2);
            }
            s1 = 0.f; s2 = 0.f; curg = g;
        }
        if (g >= 0) { float a = b2f(sX[row * LSTR + f]); s1 += a; s2 += a * a; }
    }
    if (curg >= 0) {
        atomicAdd(&gsum[(long)curg * HIDD + f], s1);
        atomicAdd(&gsq[(long)curg * HIDD + f], s2);
    }
}

// ======================= tiny finalize: stats -> Ab/Bb, zero pooled, re-zero accum ========
__global__ __launch_bounds__(128) void k_gfin(float* __restrict__ gsum, float* __restrict__ gsq,
                                              const int* __restrict__ goff,
                                              const float* __restrict__ scale, const float* __restrict__ weight,
                                              const float* __restrict__ gnb,
                                              float* __restrict__ Ab, float* __restrict__ Bb,
                                              float* __restrict__ pooled) {
    int g = blockIdx.x, f = threadIdx.x;
    float cnt = (float)max(goff[g + 1] - goff[g], 1);
    long i = (long)g * HIDD + f;
    float mean = gsum[i] / cnt;
    float ms = mean * scale[f];
    float var = gsq[i] / cnt - 2.f * ms * mean + ms * ms;
    float A = weight[f] / sqrtf(var + 1e-8f);
    Ab[i] = A;
    Bb[i] = gnb[f] - ms * A;
    pooled[i] = 0.f;
    gsum[i] = 0.f;   // clean for next layer
    gsq[i] = 0.f;
}

// ======================= norm-apply + projection GEMM + pooling (R11 verbatim) ============
__global__ __launch_bounds__(256) void k_projpool(const ushort_t* __restrict__ Hraw,
                                                  const int* __restrict__ batch,
                                                  const float* __restrict__ Ab, const float* __restrict__ Bb,
                                                  const ushort_t* __restrict__ Wt, const float* __restrict__ B,
                                                  ushort_t* __restrict__ Hn, float* __restrict__ pooled,
                                                  int store_hn) {
    __shared__ ushort_t sX[128 * LSTR];
    __shared__ int sgid[128];
    __shared__ float sA[4][128], sB[4][128];
    int tid = threadIdx.x;
    long base = (long)blockIdx.x * 128;

    if (tid < 128) sgid[tid] = (base + tid < NN) ? batch[base + tid] : -1;
    __syncthreads();
    int gmin = sgid[0];
    {
        int f = tid & 127;
#pragma unroll
        for (int s = tid >> 7; s < 4; s += 2) {
            int gg = gmin + s;
            if (gg < GGG) {
                sA[s][f] = Ab[(long)gg * HIDD + f];
                sB[s][f] = Bb[(long)gg * HIDD + f];
            }
        }
    }
    __syncthreads();

#pragma unroll
    for (int c = 0; c < 8; c++) {
        int idx = c * 256 + tid;
        int row = idx >> 4, cw = idx & 15;
        long grow = base + row;
        short8 v = (short8)0;
        if (grow < NN) {
            short8 raw = *(const short8*)(Hraw + (grow << 7) + (cw << 3));
            int slot = sgid[row] - gmin;
            const float* pA = &sA[slot][cw << 3];
            const float* pB = &sB[slot][cw << 3];
#pragma unroll
            for (int t = 0; t < 8; t++) {
                float val = b2f((ushort_t)raw[t]) * pA[t] + pB[t];
                v[t] = (short)f2b(val > 0.f ? val : 0.f);
            }
            if (store_hn) *(short8*)(Hn + (grow << 7) + (cw << 3)) = v;
        }
        *(short8*)(sX + row * LSTR + (cw << 3)) = v;
    }
    __syncthreads();   // staging wrote rows across waves

    int w = tid >> 6, l64 = tid & 63, q = l64 >> 4, l16 = l64 & 15;
    int r0 = w * 16, r1 = 64 + w * 16;
    short8 a0[4], a1[4];
#pragma unroll
    for (int c = 0; c < 4; c++) {
        a0[c] = *(const short8*)(sX + (r0 + l16) * LSTR + q * 8 + c * 32);
        a1[c] = *(const short8*)(sX + (r1 + l16) * LSTR + q * 8 + c * 32);
    }
    f32x4 acc0[8], acc1[8];
#pragma unroll
    for (int nt = 0; nt < 8; nt++) {
        int col = nt * 16 + l16;
        float bias = B[col];
        f32x4 c0 = {bias, bias, bias, bias};
        f32x4 c1 = c0;
        const ushort_t* bB = Wt + col * HIDD + q * 8;
#pragma unroll
        for (int c = 0; c < 4; c++) {
            short8 b = *(const short8*)(bB + c * 32);
            c0 = __builtin_amdgcn_mfma_f32_16x16x32_bf16(a0[c], b, c0, 0, 0, 0);
            c1 = __builtin_amdgcn_mfma_f32_16x16x32_bf16(a1[c], b, c1, 0, 0, 0);
        }
        acc0[nt] = c0; acc1[nt] = c1;
    }
    // z = relu(acc) -> own strips (wave-private; no barrier before this)
#pragma unroll
    for (int nt = 0; nt < 8; nt++) {
        int col = nt * 16 + l16;
#pragma unroll
        for (int r = 0; r < 4; r++) {
            sX[(r0 + q * 4 + r) * LSTR + col] = f2b(fmaxf(acc0[nt][r], 0.f));
            sX[(r1 + q * 4 + r) * LSTR + col] = f2b(fmaxf(acc1[nt][r], 0.f));
        }
    }
    __syncthreads();   // pooling reads all rows

    int f = tid & 127, half = tid >> 7;
    int rbeg = half * 64, rend = rbeg + 64;
    float sum = 0.f;
    int curg = -1;
    for (int row = rbeg; row < rend; row++) {
        int g = sgid[row];
        if (g != curg) {
            if (curg >= 0) atomicAdd(&pooled[(long)curg * HIDD + f], sum);
            sum = 0.f; curg = g;
        }
        if (g >= 0) sum += b2f(sX[row * LSTR + f]);
    }
    if (curg >= 0) atomicAdd(&pooled[(long)curg * HIDD + f], sum);
}

// ---- final out (layer 2): 4 graphs per 256-thread block
__global__ __launch_bounds__(256) void k_out(const float* __restrict__ pooled, const int* __restrict__ goff,
                                             const float* __restrict__ W, const float* __restrict__ B,
                                             float* __restrict__ out, int l) {
    int sub = threadIdx.x >> 6, tt = threadIdx.x & 63;
    int g = blockIdx.x * 4 + sub;
    if (g >= GGG) return;
    float cnt = (float)(goff[g + 1] - goff[g]);
    float acc = cnt * B[tt];
    const float* p = pooled + (long)g * HIDD;
    for (int k = 0; k < HIDD; k++) acc += p[k] * W[k * TGTT + tt];
    out[(long)g * (3 * TGTT) + l * TGTT + tt] = acc;
}

extern "C" void kernel_launch(void* const* d_in, const int* in_sizes, int n_in,
                              void* d_out, int out_size, void* d_ws, size_t ws_size,
                              hipStream_t stream) {
    const float* x    = (const float*)d_in[0];
    const int*   ei   = (const int*)d_in[1];
    const int*   batch= (const int*)d_in[2];
    const float* cw1  = (const float*)d_in[3];
    const float* cb1  = (const float*)d_in[4];
    const float* cw2  = (const float*)d_in[5];
    const float* cb2  = (const float*)d_in[6];
    const float* eps  = (const float*)d_in[7];
    const float* gsc  = (const float*)d_in[8];
    const float* gw   = (const float*)d_in[9];
    const float* gb   = (const float*)d_in[10];
    const float* pw1  = (const float*)d_in[11];
    const float* pb1  = (const float*)d_in[12];
    const float* pw2  = (const float*)d_in[13];
    const float* pb2  = (const float*)d_in[14];
    float* out = (float*)d_out;

    // Workspace layout IDENTICAL to R0/R9/R11 (passing). gsum/gsq alias dead bbuf (R5-validated).
    ushort_t* Xb   = (ushort_t*)d_ws;                       // N*128 bf16 — aliases Hn
    ushort_t* Hn   = Xb;
    ushort_t* Hraw = Xb + (size_t)NN * HIDD;                // N*128 bf16
    ushort_t* Wt   = Hraw + (size_t)NN * HIDD;              // 9*128*128 bf16
    float* Ab      = (float*)(Wt + (size_t)9 * HIDD * HIDD);// G*128 f32
    float* Bb      = Ab + (size_t)GGG * HIDD;               // G*128 f32
    float* pooled  = Bb + (size_t)GGG * HIDD;               // G*128 f32
    int* goff   = (int*)(pooled + (size_t)GGG * HIDD);      // G+1
    int* rowptr = goff + (GGG + 1);                         // N+1
    int* gcnt   = rowptr + (NN + 1);                        // NBK
    int* csr    = gcnt + NBK;                               // E
    unsigned int* bbuf = (unsigned int*)(csr + EE);         // NBK*CAPB (6.8 MB)
    float* gsum = (float*)bbuf;                             // G*128 f32 (aliases bbuf)
    float* gsq  = gsum + (size_t)GGG * HIDD;                // G*128 f32

    hipMemsetAsync(gcnt, 0, NBK * sizeof(int), stream);
    k_pro<<<ABLK + CVT2 + 9 + 3, 256, 0, stream>>>(x, Xb, cw1, cw2, pw1, Wt, batch, goff, ei, gcnt, bbuf);
    k_csr<<<NBK, 1024, 0, stream>>>(gcnt, bbuf, rowptr, csr);
    // bbuf dead from here; zero its head for gsum/gsq (stream-ordered after k_csr)
    hipMemsetAsync(gsum, 0, (size_t)2 * GGG * HIDD * sizeof(float), stream);

    for (int l = 0; l < 3; l++) {
        const ushort_t* hin = (l == 0) ? Xb : Hn;
        ushort_t* Wt1 = Wt + (size_t)(l * 3 + 0) * HIDD * HIDD;
        ushort_t* Wt2 = Wt + (size_t)(l * 3 + 1) * HIDD * HIDD;
        ushort_t* Wtp = Wt + (size_t)(l * 3 + 2) * HIDD * HIDD;
        int grid = GBLK + (l > 0 ? OUTB : 0);
        k_gmlp<<<grid, 256, 0, stream>>>(hin, rowptr, csr, batch, eps, l,
                                         Wt1, cb1 + l * HIDD, Wt2, cb2 + l * HIDD, Hraw,
                                         gsum, gsq,
                                         pooled, goff,
                                         pw2 + (size_t)(l - 1) * HIDD * TGTT, pb2 + (l - 1) * TGTT,
                                         out, l - 1);
        k_gfin<<<GGG, 128, 0, stream>>>(gsum, gsq, goff, gsc + l * HIDD, gw + l * HIDD, gb + l * HIDD,
                                        Ab, Bb, pooled);
        k_projpool<<<GBLK, 256, 0, stream>>>(Hraw, batch, Ab, Bb,
                                             Wtp, pb1 + l * HIDD, Hn, pooled, (l < 2) ? 1 : 0);
    }
    k_out<<<OUTB, 256, 0, stream>>>(pooled, goff, pw2 + (size_t)2 * HIDD * TGTT, pb2 + 2 * TGTT, out, 2);
}

// Round 14
// 582.663 us; speedup vs baseline: 1.1391x; 1.0121x over previous
//
#include <hip/hip_runtime.h>

#define NN 100000
#define EE 1600000
#define HIDD 128
#define TGTT 64
#define GGG 512
#define NBK 98          // buckets of 1024 nodes
#define CAPB 17408      // bucket capacity: mean 16327 +8.5 sd
#define ABLK 800        // binA blocks, EPB edges each
#define EPB 2000        // edges per binA block
#define CVT2 512        // cvt grid-stride blocks
#define LSTR 136        // sX row stride (shorts)
#define GBLK 782        // gmlp/projpool main blocks (128 rows)
#define OUTB 128        // out filler blocks (4 graphs each @256 thr)

typedef unsigned short ushort_t;
typedef __attribute__((ext_vector_type(8))) short short8;
typedef __attribute__((ext_vector_type(4))) float f32x4;
typedef __attribute__((ext_vector_type(4))) unsigned short us4;

__device__ __forceinline__ float b2f(ushort_t u) {
    union { unsigned int i; float f; } v; v.i = ((unsigned int)u) << 16; return v.f;
}
__device__ __forceinline__ ushort_t f2b(float f) {
    union { float f; unsigned int i; } v; v.f = f;
    unsigned int r = (v.i + 0x7fffu + ((v.i >> 16) & 1u)) >> 16;
    return (ushort_t)r;
}

// ======================= prologue: binA | cvt(grid-stride) | weight-prep | goff ============
__global__ __launch_bounds__(256) void k_pro(const float* __restrict__ x, ushort_t* __restrict__ Xb,
                                             const float* __restrict__ cw1, const float* __restrict__ cw2,
                                             const float* __restrict__ pw1, ushort_t* __restrict__ Wt,
                                             const int* __restrict__ batch, int* __restrict__ goff,
                                             const int* __restrict__ ei, int* __restrict__ gcnt,
                                             unsigned int* __restrict__ bbuf) {
    __shared__ int cnt[NBK], base[NBK], cur[NBK];
    int b = blockIdx.x, t = threadIdx.x;

    if (b < ABLK) {   // ---- binA edge binning
        if (t < NBK) cnt[t] = 0;
        __syncthreads();
        int e0 = b * EPB;
        int e1 = min(e0 + EPB, EE);
        for (int e = e0 + t; e < e1; e += 256)
            atomicAdd(&cnt[ei[EE + e] >> 10], 1);
        __syncthreads();
        if (t < NBK) { base[t] = atomicAdd(&gcnt[t], cnt[t]); cur[t] = 0; }
        __syncthreads();
        for (int e = e0 + t; e < e1; e += 256) {
            int s = ei[e], d = ei[EE + e];
            int bk = d >> 10;
            int off = base[bk] + atomicAdd(&cur[bk], 1);
            if (off < CAPB)
                bbuf[(long)bk * CAPB + off] = (unsigned int)s | (((unsigned int)d & 1023u) << 17);
        }
        return;
    }
    b -= ABLK;
    if (b < CVT2) {   // ---- x -> bf16, grid-stride streaming
        long total = (long)NN * HIDD / 4;
        long step = (long)CVT2 * 256;
        for (long i = (long)b * 256 + t; i < total; i += step) {
            float4 v = ((const float4*)x)[i];
            us4 o; o.x = f2b(v.x); o.y = f2b(v.y); o.z = f2b(v.z); o.w = f2b(v.w);
            ((us4*)Xb)[i] = o;
        }
        return;
    }
    b -= CVT2;
    if (b < 9) {      // ---- weight transpose: coalesced read, strided write
        int l = b / 3, j = b % 3;
        const float* src = (j == 0 ? cw1 : j == 1 ? cw2 : pw1) + (size_t)l * HIDD * HIDD;
        ushort_t* dst = Wt + (size_t)b * HIDD * HIDD;
        for (int i = t; i < HIDD * HIDD; i += 256)
            dst[(i & 127) * HIDD + (i >> 7)] = f2b(src[i]);
        return;
    }
    b -= 9;
    {                 // ---- goff binary search (3 blocks)
        int g = b * 256 + t;
        if (g > GGG) return;
        int lo = 0, hi = NN;
        while (lo < hi) { int mid = (lo + hi) >> 1; if (batch[mid] < g) lo = mid + 1; else hi = mid; }
        goff[g] = lo;
    }
}

// ======================= CSR phase B, 1024 threads (1 node/thread) =======================
__global__ __launch_bounds__(1024) void k_csr(const int* __restrict__ gcnt,
                                              const unsigned int* __restrict__ bbuf,
                                              int* __restrict__ rowptr, int* __restrict__ csr) {
    __shared__ int ldeg[1024], tsum[1024], sb[NBK];
    int b = blockIdx.x, t = threadIdx.x;
    if (t < NBK) sb[t] = gcnt[t];
    ldeg[t] = 0;
    __syncthreads();
    if (t == 0) { int a = 0; for (int i = 0; i < NBK; i++) { int v = sb[i]; sb[i] = a; a += v; } }
    __syncthreads();
    int cnt = min(gcnt[b], CAPB);
    int base = sb[b];
    const unsigned int* bb = bbuf + (long)b * CAPB;
    for (int i = t; i < cnt; i += 1024) atomicAdd(&ldeg[bb[i] >> 17], 1);
    __syncthreads();
    int d0 = ldeg[t];
    tsum[t] = d0;
    __syncthreads();
    for (int off = 1; off < 1024; off <<= 1) {
        int u = (t >= off) ? tsum[t - off] : 0;
        __syncthreads();
        tsum[t] += u;
        __syncthreads();
    }
    int p0 = base + tsum[t] - d0;
    int gnode = b * 1024 + t;
    if (gnode < NN) rowptr[gnode] = p0;
    if (b == NBK - 1 && t == 0) rowptr[NN] = EE;
    ldeg[t] = p0;          // reuse as scatter cursor
    __syncthreads();
    for (int i = t; i < cnt; i += 1024) {
        unsigned int en = bb[i];
        int pos = atomicAdd(&ldeg[en >> 17], 1);
        csr[pos] = (int)(en & 0x1FFFFu);
    }
}

// ======================= fused gather + 2-layer MLP + GraphNorm stats (R13 verbatim) ======
__global__ __launch_bounds__(256) void k_gmlp(const ushort_t* __restrict__ hin,
                                              const int* __restrict__ rowptr,
                                              const int* __restrict__ csr,
                                              const int* __restrict__ batch,
                                              const float* __restrict__ eps, int l,
                                              const ushort_t* __restrict__ Wt1, const float* __restrict__ B1,
                                              const ushort_t* __restrict__ Wt2, const float* __restrict__ B2,
                                              ushort_t* __restrict__ Y,
                                              float* __restrict__ gsum, float* __restrict__ gsq,
                                              const float* __restrict__ pooledP, const int* __restrict__ goff,
                                              const float* __restrict__ WoP, const float* __restrict__ BoP,
                                              float* __restrict__ outP, int lprev) {
    __shared__ ushort_t sX[128 * LSTR];
    __shared__ int sgid[128];
    int tid = threadIdx.x;

    if (blockIdx.x >= GBLK) {     // ---- filler: out[g] for previous layer (4 graphs/block)
        if (lprev < 0) return;
        int ob = blockIdx.x - GBLK;
        int sub = tid >> 6, tt = tid & 63;
        int g = ob * 4 + sub;
        if (g >= GGG) return;
        float cntg = (float)(goff[g + 1] - goff[g]);
        float acc = cntg * BoP[tt];
        const float* p = pooledP + (long)g * HIDD;
        for (int k = 0; k < HIDD; k++) acc += p[k] * WoP[k * TGTT + tt];
        outP[(long)g * (3 * TGTT) + lprev * TGTT + tt] = acc;
        return;
    }

    long base = (long)blockIdx.x * 128;
    int lane = tid & 15, ng = tid >> 4;
    int off = lane << 3;
    float e1 = 1.0f + eps[l];

    if (tid < 128) sgid[tid] = (base + tid < NN) ? batch[base + tid] : -1;

    // ---- gather phase: 8 passes x 16 nodes
#pragma unroll 1
    for (int it = 0; it < 8; it++) {
        int row = it * 16 + ng;
        long node = base + row;
        short8 o = (short8)0;
        if (node < NN) {
            short8 h = *(const short8*)(hin + (node << 7) + off);
            float acc[8];
#pragma unroll
            for (int t = 0; t < 8; t++) acc[t] = e1 * b2f((ushort_t)h[t]);
            int jb = rowptr[node], je = rowptr[node + 1];
            int j = jb;
            for (; j + 8 <= je; j += 8) {
                int s0 = csr[j], s1 = csr[j + 1], s2 = csr[j + 2], s3 = csr[j + 3];
                int s4 = csr[j + 4], s5 = csr[j + 5], s6 = csr[j + 6], s7 = csr[j + 7];
                short8 v0 = *(const short8*)(hin + ((long)s0 << 7) + off);
                short8 v1 = *(const short8*)(hin + ((long)s1 << 7) + off);
                short8 v2 = *(const short8*)(hin + ((long)s2 << 7) + off);
                short8 v3 = *(const short8*)(hin + ((long)s3 << 7) + off);
                short8 v4 = *(const short8*)(hin + ((long)s4 << 7) + off);
                short8 v5 = *(const short8*)(hin + ((long)s5 << 7) + off);
                short8 v6 = *(const short8*)(hin + ((long)s6 << 7) + off);
                short8 v7 = *(const short8*)(hin + ((long)s7 << 7) + off);
#pragma unroll
                for (int t = 0; t < 8; t++)
                    acc[t] += ((b2f((ushort_t)v0[t]) + b2f((ushort_t)v1[t])) +
                               (b2f((ushort_t)v2[t]) + b2f((ushort_t)v3[t]))) +
                              ((b2f((ushort_t)v4[t]) + b2f((ushort_t)v5[t])) +
                               (b2f((ushort_t)v6[t]) + b2f((ushort_t)v7[t])));
            }
            for (; j + 4 <= je; j += 4) {
                int s0 = csr[j], s1 = csr[j + 1], s2 = csr[j + 2], s3 = csr[j + 3];
                short8 v0 = *(const short8*)(hin + ((long)s0 << 7) + off);
                short8 v1 = *(const short8*)(hin + ((long)s1 << 7) + off);
                short8 v2 = *(const short8*)(hin + ((long)s2 << 7) + off);
                short8 v3 = *(const short8*)(hin + ((long)s3 << 7) + off);
#pragma unroll
                for (int t = 0; t < 8; t++)
                    acc[t] += (b2f((ushort_t)v0[t]) + b2f((ushort_t)v1[t])) +
                              (b2f((ushort_t)v2[t]) + b2f((ushort_t)v3[t]));
            }
            for (; j < je; j++) {
                int s = csr[j];
                short8 v = *(const short8*)(hin + ((long)s << 7) + off);
#pragma unroll
                for (int t = 0; t < 8; t++) acc[t] += b2f((ushort_t)v[t]);
            }
#pragma unroll
            for (int t = 0; t < 8; t++) o[t] = (short)f2b(acc[t]);
        }
        *(short8*)(sX + row * LSTR + off) = o;
    }
    __syncthreads();   // gather rows cross waves

    // ---- MLP: 4 waves x 2 private strips; no barriers until stats
    int w = tid >> 6, l64 = tid & 63, q = l64 >> 4, l16 = l64 & 15;
    int r0 = w * 16, r1 = 64 + w * 16;
    short8 a0[4], a1[4];
#pragma unroll
    for (int c = 0; c < 4; c++) {
        a0[c] = *(const short8*)(sX + (r0 + l16) * LSTR + q * 8 + c * 32);
        a1[c] = *(const short8*)(sX + (r1 + l16) * LSTR + q * 8 + c * 32);
    }
    f32x4 acc0[8], acc1[8];
#pragma unroll
    for (int nt = 0; nt < 8; nt++) {
        int col = nt * 16 + l16;
        float bias = B1[col];
        f32x4 c0 = {bias, bias, bias, bias};
        f32x4 c1 = c0;
        const ushort_t* bB = Wt1 + col * HIDD + q * 8;
#pragma unroll
        for (int c = 0; c < 4; c++) {
            short8 b = *(const short8*)(bB + c * 32);
            c0 = __builtin_amdgcn_mfma_f32_16x16x32_bf16(a0[c], b, c0, 0, 0, 0);
            c1 = __builtin_amdgcn_mfma_f32_16x16x32_bf16(a1[c], b, c1, 0, 0, 0);
        }
        acc0[nt] = c0; acc1[nt] = c1;
    }
    // T = relu(acc) -> own strips (wave-private)
#pragma unroll
    for (int nt = 0; nt < 8; nt++) {
        int col = nt * 16 + l16;
#pragma unroll
        for (int r = 0; r < 4; r++) {
            sX[(r0 + q * 4 + r) * LSTR + col] = f2b(fmaxf(acc0[nt][r], 0.f));
            sX[(r1 + q * 4 + r) * LSTR + col] = f2b(fmaxf(acc1[nt][r], 0.f));
        }
    }
    // GEMM2: T @ Wt2 + B2 -> Y (global) and h -> sX (wave-private rows, for stats)
#pragma unroll
    for (int c = 0; c < 4; c++) {
        a0[c] = *(const short8*)(sX + (r0 + l16) * LSTR + q * 8 + c * 32);
        a1[c] = *(const short8*)(sX + (r1 + l16) * LSTR + q * 8 + c * 32);
    }
#pragma unroll
    for (int nt = 0; nt < 8; nt++) {
        int col = nt * 16 + l16;
        float bias = B2[col];
        f32x4 c0 = {bias, bias, bias, bias};
        f32x4 c1 = c0;
        const ushort_t* bB = Wt2 + col * HIDD + q * 8;
#pragma unroll
        for (int c = 0; c < 4; c++) {
            short8 b = *(const short8*)(bB + c * 32);
            c0 = __builtin_amdgcn_mfma_f32_16x16x32_bf16(a0[c], b, c0, 0, 0, 0);
            c1 = __builtin_amdgcn_mfma_f32_16x16x32_bf16(a1[c], b, c1, 0, 0, 0);
        }
#pragma unroll
        for (int r = 0; r < 4; r++) {
            long row0 = base + r0 + q * 4 + r;
            long row1 = base + r1 + q * 4 + r;
            ushort_t h0 = f2b(c0[r]), h1 = f2b(c1[r]);
            if (row0 < NN) Y[(row0 << 7) + col] = h0;
            if (row1 < NN) Y[(row1 << 7) + col] = h1;
            sX[(r0 + q * 4 + r) * LSTR + col] = h0;
            sX[(r1 + q * 4 + r) * LSTR + col] = h1;
        }
    }
    __syncthreads();   // stats read all rows (+ sgid visible)

    // ---- segmented per-graph (sum, sumsq) -> atomics
    int f = tid & 127, half = tid >> 7;
    int rbeg = half * 64, rend = rbeg + 64;
    float s1 = 0.f, s2 = 0.f;
    int curg = -1;
    for (int row = rbeg; row < rend; row++) {
        int g = sgid[row];
        if (g != curg) {
            if (curg >= 0) {
                atomicAdd(&gsum[(long)curg * HIDD + f], s1);
                atomicAdd(&gsq[(long)curg * HIDD + f], s2);
            }
            s1 = 0.f; s2 = 0.f; curg = g;
        }
        if (g >= 0) { float a = b2f(sX[row * LSTR + f]); s1 += a; s2 += a * a; }
    }
    if (curg >= 0) {
        atomicAdd(&gsum[(long)curg * HIDD + f], s1);
        atomicAdd(&gsq[(long)curg * HIDD + f], s2);
    }
}

// ======================= norm-apply + projection GEMM + pooling, INLINE A/B ===============
// k_gfin deleted: each block computes A/B for its <=4 spanned graphs directly from
// gsum/gsq (L2-hot from gmlp's atomics). Removes a per-layer launch + 2 sync boundaries.
// pooled/gsum/gsq are per-layer regions, zeroed ONCE upfront — no re-zeroing pass.
__global__ __launch_bounds__(256) void k_projpool(const ushort_t* __restrict__ Hraw,
                                                  const int* __restrict__ batch,
                                                  const float* __restrict__ gsum, const float* __restrict__ gsq,
                                                  const int* __restrict__ goff,
                                                  const float* __restrict__ scale, const float* __restrict__ weight,
                                                  const float* __restrict__ gnbp,
                                                  const ushort_t* __restrict__ Wt, const float* __restrict__ B,
                                                  ushort_t* __restrict__ Hn, float* __restrict__ pooled,
                                                  int store_hn) {
    __shared__ ushort_t sX[128 * LSTR];
    __shared__ int sgid[128];
    __shared__ float sA[4][128], sB[4][128];
    int tid = threadIdx.x;
    long base = (long)blockIdx.x * 128;

    if (tid < 128) sgid[tid] = (base + tid < NN) ? batch[base + tid] : -1;
    __syncthreads();
    int gmin = sgid[0];
    {
        int f = tid & 127;
#pragma unroll
        for (int s = tid >> 7; s < 4; s += 2) {
            int gg = gmin + s;
            if (gg < GGG) {
                float cntg = (float)max(goff[gg + 1] - goff[gg], 1);
                long i = (long)gg * HIDD + f;
                float mean = gsum[i] / cntg;
                float ms = mean * scale[f];
                float var = gsq[i] / cntg - 2.f * ms * mean + ms * ms;
                float A = weight[f] / sqrtf(var + 1e-8f);
                sA[s][f] = A;
                sB[s][f] = gnbp[f] - ms * A;
            }
        }
    }
    __syncthreads();

#pragma unroll
    for (int c = 0; c < 8; c++) {
        int idx = c * 256 + tid;
        int row = idx >> 4, cw = idx & 15;
        long grow = base + row;
        short8 v = (short8)0;
        if (grow < NN) {
            short8 raw = *(const short8*)(Hraw + (grow << 7) + (cw << 3));
            int slot = sgid[row] - gmin;
            const float* pA = &sA[slot][cw << 3];
            const float* pB = &sB[slot][cw << 3];
#pragma unroll
            for (int t = 0; t < 8; t++) {
                float val = b2f((ushort_t)raw[t]) * pA[t] + pB[t];
                v[t] = (short)f2b(val > 0.f ? val : 0.f);
            }
            if (store_hn) *(short8*)(Hn + (grow << 7) + (cw << 3)) = v;
        }
        *(short8*)(sX + row * LSTR + (cw << 3)) = v;
    }
    __syncthreads();   // staging wrote rows across waves

    int w = tid >> 6, l64 = tid & 63, q = l64 >> 4, l16 = l64 & 15;
    int r0 = w * 16, r1 = 64 + w * 16;
    short8 a0[4], a1[4];
#pragma unroll
    for (int c = 0; c < 4; c++) {
        a0[c] = *(const short8*)(sX + (r0 + l16) * LSTR + q * 8 + c * 32);
        a1[c] = *(const short8*)(sX + (r1 + l16) * LSTR + q * 8 + c * 32);
    }
    f32x4 acc0[8], acc1[8];
#pragma unroll
    for (int nt = 0; nt < 8; nt++) {
        int col = nt * 16 + l16;
        float bias = B[col];
        f32x4 c0 = {bias, bias, bias, bias};
        f32x4 c1 = c0;
        const ushort_t* bB = Wt + col * HIDD + q * 8;
#pragma unroll
        for (int c = 0; c < 4; c++) {
            short8 b = *(const short8*)(bB + c * 32);
            c0 = __builtin_amdgcn_mfma_f32_16x16x32_bf16(a0[c], b, c0, 0, 0, 0);
            c1 = __builtin_amdgcn_mfma_f32_16x16x32_bf16(a1[c], b, c1, 0, 0, 0);
        }
        acc0[nt] = c0; acc1[nt] = c1;
    }
    // z = relu(acc) -> own strips (wave-private; no barrier before this)
#pragma unroll
    for (int nt = 0; nt < 8; nt++) {
        int col = nt * 16 + l16;
#pragma unroll
        for (int r = 0; r < 4; r++) {
            sX[(r0 + q * 4 + r) * LSTR + col] = f2b(fmaxf(acc0[nt][r], 0.f));
            sX[(r1 + q * 4 + r) * LSTR + col] = f2b(fmaxf(acc1[nt][r], 0.f));
        }
    }
    __syncthreads();   // pooling reads all rows

    int f = tid & 127, half = tid >> 7;
    int rbeg = half * 64, rend = rbeg + 64;
    float sum = 0.f;
    int curg = -1;
    for (int row = rbeg; row < rend; row++) {
        int g = sgid[row];
        if (g != curg) {
            if (curg >= 0) atomicAdd(&pooled[(long)curg * HIDD + f], sum);
            sum = 0.f; curg = g;
        }
        if (g >= 0) sum += b2f(sX[row * LSTR + f]);
    }
    if (curg >= 0) atomicAdd(&pooled[(long)curg * HIDD + f], sum);
}

// ---- final out (layer 2): 4 graphs per 256-thread block
__global__ __launch_bounds__(256) void k_out(const float* __restrict__ pooled, const int* __restrict__ goff,
                                             const float* __restrict__ W, const float* __restrict__ B,
                                             float* __restrict__ out, int l) {
    int sub = threadIdx.x >> 6, tt = threadIdx.x & 63;
    int g = blockIdx.x * 4 + sub;
    if (g >= GGG) return;
    float cnt = (float)(goff[g + 1] - goff[g]);
    float acc = cnt * B[tt];
    const float* p = pooled + (long)g * HIDD;
    for (int k = 0; k < HIDD; k++) acc += p[k] * W[k * TGTT + tt];
    out[(long)g * (3 * TGTT) + l * TGTT + tt] = acc;
}

extern "C" void kernel_launch(void* const* d_in, const int* in_sizes, int n_in,
                              void* d_out, int out_size, void* d_ws, size_t ws_size,
                              hipStream_t stream) {
    const float* x    = (const float*)d_in[0];
    const int*   ei   = (const int*)d_in[1];
    const int*   batch= (const int*)d_in[2];
    const float* cw1  = (const float*)d_in[3];
    const float* cb1  = (const float*)d_in[4];
    const float* cw2  = (const float*)d_in[5];
    const float* cb2  = (const float*)d_in[6];
    const float* eps  = (const float*)d_in[7];
    const float* gsc  = (const float*)d_in[8];
    const float* gw   = (const float*)d_in[9];
    const float* gb   = (const float*)d_in[10];
    const float* pw1  = (const float*)d_in[11];
    const float* pb1  = (const float*)d_in[12];
    const float* pw2  = (const float*)d_in[13];
    const float* pb2  = (const float*)d_in[14];
    float* out = (float*)d_out;

    // Workspace layout IDENTICAL to R0/R9/R11/R13 (passing). Per-layer accumulators
    // (gsum[3], gsq[3], pooled[3] = 2.36MB) alias dead bbuf (6.8MB), zeroed once.
    ushort_t* Xb   = (ushort_t*)d_ws;                       // N*128 bf16 — aliases Hn
    ushort_t* Hn   = Xb;
    ushort_t* Hraw = Xb + (size_t)NN * HIDD;                // N*128 bf16
    ushort_t* Wt   = Hraw + (size_t)NN * HIDD;              // 9*128*128 bf16
    float* Ab_unused = (float*)(Wt + (size_t)9 * HIDD * HIDD); // kept for layout
    float* Bb_unused = Ab_unused + (size_t)GGG * HIDD;
    float* pooled_unused = Bb_unused + (size_t)GGG * HIDD;
    int* goff   = (int*)(pooled_unused + (size_t)GGG * HIDD); // G+1
    int* rowptr = goff + (GGG + 1);                         // N+1
    int* gcnt   = rowptr + (NN + 1);                        // NBK
    int* csr    = gcnt + NBK;                               // E
    unsigned int* bbuf = (unsigned int*)(csr + EE);         // NBK*CAPB (6.8 MB)
    float* acc3 = (float*)bbuf;                             // 9 * G*128 f32 on dead bbuf
    const size_t R = (size_t)GGG * HIDD;                    // region stride
    // layout: gsum[l]=acc3+l*R, gsq[l]=acc3+(3+l)*R, pooled[l]=acc3+(6+l)*R

    hipMemsetAsync(gcnt, 0, NBK * sizeof(int), stream);
    k_pro<<<ABLK + CVT2 + 9 + 3, 256, 0, stream>>>(x, Xb, cw1, cw2, pw1, Wt, batch, goff, ei, gcnt, bbuf);
    k_csr<<<NBK, 1024, 0, stream>>>(gcnt, bbuf, rowptr, csr);
    // bbuf dead from here; zero all per-layer accumulators once (stream-ordered after k_csr)
    hipMemsetAsync(acc3, 0, 9 * R * sizeof(float), stream);

    for (int l = 0; l < 3; l++) {
        const ushort_t* hin = (l == 0) ? Xb : Hn;
        ushort_t* Wt1 = Wt + (size_t)(l * 3 + 0) * HIDD * HIDD;
        ushort_t* Wt2 = Wt + (size_t)(l * 3 + 1) * HIDD * HIDD;
        ushort_t* Wtp = Wt + (size_t)(l * 3 + 2) * HIDD * HIDD;
        float* gsum_l   = acc3 + (size_t)l * R;
        float* gsq_l    = acc3 + (size_t)(3 + l) * R;
        float* pooled_l = acc3 + (size_t)(6 + l) * R;
        const float* pooled_prev = acc3 + (size_t)(6 + (l > 0 ? l - 1 : 0)) * R;
        int grid = GBLK + (l > 0 ? OUTB : 0);
        k_gmlp<<<grid, 256, 0, stream>>>(hin, rowptr, csr, batch, eps, l,
                                         Wt1, cb1 + l * HIDD, Wt2, cb2 + l * HIDD, Hraw,
                                         gsum_l, gsq_l,
                                         pooled_prev, goff,
                                         pw2 + (size_t)(l - 1) * HIDD * TGTT, pb2 + (l - 1) * TGTT,
                                         out, l - 1);
        k_projpool<<<GBLK, 256, 0, stream>>>(Hraw, batch, gsum_l, gsq_l, goff,
                                             gsc + l * HIDD, gw + l * HIDD, gb + l * HIDD,
                                             Wtp, pb1 + l * HIDD, Hn, pooled_l, (l < 2) ? 1 : 0);
    }
    k_out<<<OUTB, 256, 0, stream>>>(acc3 + (size_t)(6 + 2) * R, goff,
                                    pw2 + (size_t)2 * HIDD * TGTT, pb2 + 2 * TGTT, out, 2);
}